// Round 1
// baseline (4164.943 us; speedup 1.0000x reference)
//
#include <hip/hip_runtime.h>
#include <math.h>

// Dims fixed by the reference: MEM = NF = MSG = 256.
#define MEMD 256
#define BM   32     // event rows per block; 100000 % 32 == 0 -> 3125 blocks
#define NT   256    // threads per block; thread t owns output column t

__device__ __forceinline__ float sigmoidf(float x) {
    return 1.0f / (1.0f + __expf(-x));
}

// acc[r] += sum_k A[r][k] * Wcol[k*256]   (W column-major access, coalesced across lanes)
__device__ __forceinline__ void col_fma(const float (*A)[MEMD], const float* Wcol, float* acc) {
    for (int k4 = 0; k4 < 64; ++k4) {
        float w0 = Wcol[(4 * k4 + 0) * MEMD];
        float w1 = Wcol[(4 * k4 + 1) * MEMD];
        float w2 = Wcol[(4 * k4 + 2) * MEMD];
        float w3 = Wcol[(4 * k4 + 3) * MEMD];
#pragma unroll
        for (int r = 0; r < BM; ++r) {
            float4 av = ((const float4*)A[r])[k4];
            acc[r] = fmaf(av.x, w0, acc[r]);
            acc[r] = fmaf(av.y, w1, acc[r]);
            acc[r] = fmaf(av.z, w2, acc[r]);
            acc[r] = fmaf(av.w, w3, acc[r]);
        }
    }
}

// acc[r] += sum_k A[r][k] * wrow[k]   (per-thread weight row, sequential f4 reads)
__device__ __forceinline__ void row_fma(const float (*A)[MEMD], const float* wrow, float* acc) {
    for (int k4 = 0; k4 < 64; ++k4) {
        float4 wv = ((const float4*)wrow)[k4];
#pragma unroll
        for (int r = 0; r < BM; ++r) {
            float4 av = ((const float4*)A[r])[k4];
            acc[r] = fmaf(av.x, wv.x, acc[r]);
            acc[r] = fmaf(av.y, wv.y, acc[r]);
            acc[r] = fmaf(av.z, wv.z, acc[r]);
            acc[r] = fmaf(av.w, wv.w, acc[r]);
        }
    }
}

__global__ __launch_bounds__(NT, 2)
void tgn_fused(const float* __restrict__ memory,
               const int*   __restrict__ node_idxs,
               const float* __restrict__ nf,
               const float* __restrict__ ef,
               const float* __restrict__ tstamps,
               const float* __restrict__ W1, const float* __restrict__ b1,
               const float* __restrict__ W2, const float* __restrict__ b2,
               const float* __restrict__ Wih, const float* __restrict__ Whh,
               const float* __restrict__ bih, const float* __restrict__ bhh,
               float* __restrict__ out_mem, float* __restrict__ out_msg,
               float* __restrict__ out_lu)
{
    __shared__ float hs[BM][MEMD];   // gathered node memory (h), 32 KB
    __shared__ float ms[BM][MEMD];   // relu(t1), then m, 32 KB
    __shared__ float xs[BM][64];     // nf/ef K-chunk, 8 KB
    __shared__ int   idxs[BM];

    const int t = threadIdx.x;
    const int row0 = blockIdx.x * BM;

    if (t < BM) idxs[t] = node_idxs[row0 + t];
    __syncthreads();

    // Gather h = memory[idx] into LDS (coalesced: 64 lanes read 1 KB/row)
    for (int j = t; j < BM * 64; j += NT) {
        int r = j >> 6, c4 = j & 63;
        ((float4*)hs[r])[c4] = ((const float4*)(memory + (size_t)idxs[r] * MEMD))[c4];
    }
    __syncthreads();

    // ---------- layer 1: t1 = [nf | h | ef] @ W1 + b1 ----------
    float acc[BM];
    {
        float b = b1[t];
#pragma unroll
        for (int r = 0; r < BM; ++r) acc[r] = b;
    }

    // middle segment (h), W1 rows 256..511, straight from LDS
    col_fma(hs, W1 + 256 * MEMD + t, acc);

    // nf (W1 rows 0..255) and ef (rows 512..767), staged in 64-wide K chunks
    for (int seg = 0; seg < 2; ++seg) {
        const float* src = seg ? ef : nf;
        const int kbase = seg ? 512 : 0;
        for (int kb = 0; kb < 256; kb += 64) {
            __syncthreads();
#pragma unroll
            for (int i = 0; i < 2; ++i) {
                int j = i * NT + t;
                int r = j >> 4, c4 = j & 15;
                ((float4*)xs[r])[c4] =
                    ((const float4*)(src + (size_t)(row0 + r) * MEMD))[(kb >> 2) + c4];
            }
            __syncthreads();
            const float* Wcol = W1 + (size_t)(kbase + kb) * MEMD + t;
            for (int k4 = 0; k4 < 16; ++k4) {
                float w0 = Wcol[(4 * k4 + 0) * MEMD];
                float w1 = Wcol[(4 * k4 + 1) * MEMD];
                float w2 = Wcol[(4 * k4 + 2) * MEMD];
                float w3 = Wcol[(4 * k4 + 3) * MEMD];
#pragma unroll
                for (int r = 0; r < BM; ++r) {
                    float4 xv = ((const float4*)xs[r])[k4];
                    acc[r] = fmaf(xv.x, w0, acc[r]);
                    acc[r] = fmaf(xv.y, w1, acc[r]);
                    acc[r] = fmaf(xv.z, w2, acc[r]);
                    acc[r] = fmaf(xv.w, w3, acc[r]);
                }
            }
        }
    }

    // relu(t1) -> ms
    __syncthreads();
#pragma unroll
    for (int r = 0; r < BM; ++r) ms[r][t] = fmaxf(acc[r], 0.0f);
    __syncthreads();

    // ---------- layer 2: m = relu(t1) @ W2 + b2 ----------
    float acc2[BM];
    {
        float b = b2[t];
#pragma unroll
        for (int r = 0; r < BM; ++r) acc2[r] = b;
    }
    col_fma(ms, W2 + t, acc2);

    // write m to out_msg; then overwrite ms with m (needed for gx)
#pragma unroll
    for (int r = 0; r < BM; ++r)
        out_msg[(size_t)idxs[r] * MEMD + t] = acc2[r];
    __syncthreads();   // all layer-2 reads of ms done
#pragma unroll
    for (int r = 0; r < BM; ++r) ms[r][t] = acc2[r];
    __syncthreads();

    // ---------- GRU gates (torch order r,z,n) ----------
    // gate r: sigmoid(m @ Wih[0:256].T + bih[0:256] + h @ Whh[0:256].T + bhh[0:256]) col t
    float rv[BM];
    {
        float b = bih[t] + bhh[t];
#pragma unroll
        for (int r = 0; r < BM; ++r) rv[r] = b;
        row_fma(ms, Wih + (size_t)t * MEMD, rv);
        row_fma(hs, Whh + (size_t)t * MEMD, rv);
#pragma unroll
        for (int r = 0; r < BM; ++r) rv[r] = sigmoidf(rv[r]);
    }
    // gate z
    float zv[BM];
    {
        float b = bih[MEMD + t] + bhh[MEMD + t];
#pragma unroll
        for (int r = 0; r < BM; ++r) zv[r] = b;
        row_fma(ms, Wih + (size_t)(MEMD + t) * MEMD, zv);
        row_fma(hs, Whh + (size_t)(MEMD + t) * MEMD, zv);
#pragma unroll
        for (int r = 0; r < BM; ++r) zv[r] = sigmoidf(zv[r]);
    }
    // gate n: tanh(xn + r * hn), keep x-part and h-part separate
    float axn[BM], ahn[BM];
    {
        float bx = bih[2 * MEMD + t];
        float bh = bhh[2 * MEMD + t];
#pragma unroll
        for (int r = 0; r < BM; ++r) { axn[r] = bx; ahn[r] = bh; }
        row_fma(ms, Wih + (size_t)(2 * MEMD + t) * MEMD, axn);
        row_fma(hs, Whh + (size_t)(2 * MEMD + t) * MEMD, ahn);
    }

    // h_new = (1-z)*n + z*h = n + z*(h-n); scatter
#pragma unroll
    for (int r = 0; r < BM; ++r) {
        float n = tanhf(axn[r] + rv[r] * ahn[r]);
        float h = hs[r][t];
        float hn = fmaf(zv[r], h - n, n);
        out_mem[(size_t)idxs[r] * MEMD + t] = hn;
    }
    if (t < BM) out_lu[idxs[t]] = tstamps[row0 + t];
}

extern "C" void kernel_launch(void* const* d_in, const int* in_sizes, int n_in,
                              void* d_out, int out_size, void* d_ws, size_t ws_size,
                              hipStream_t stream)
{
    const float* memory      = (const float*)d_in[0];
    const float* messages    = (const float*)d_in[1];
    const float* last_update = (const float*)d_in[2];
    const int*   node_idxs   = (const int*)  d_in[3];
    const float* nf          = (const float*)d_in[4];
    const float* ef          = (const float*)d_in[5];
    const float* tstamps     = (const float*)d_in[6];
    const float* W1          = (const float*)d_in[7];
    const float* b1          = (const float*)d_in[8];
    const float* W2          = (const float*)d_in[9];
    const float* b2          = (const float*)d_in[10];
    const float* Wih         = (const float*)d_in[11];
    const float* Whh         = (const float*)d_in[12];
    const float* bih         = (const float*)d_in[13];
    const float* bhh         = (const float*)d_in[14];

    const int n_nodes = in_sizes[2];   // 300000
    const int Bn      = in_sizes[3];   // 100000

    float* out_mem = (float*)d_out;
    float* out_msg = out_mem + (size_t)n_nodes * MEMD;
    float* out_lu  = out_msg + (size_t)n_nodes * MEMD;

    // Pass-through copies (graph-capture-safe d2d); scattered rows overwritten below.
    hipMemcpyAsync(out_mem, memory,      (size_t)n_nodes * MEMD * sizeof(float),
                   hipMemcpyDeviceToDevice, stream);
    hipMemcpyAsync(out_msg, messages,    (size_t)n_nodes * MEMD * sizeof(float),
                   hipMemcpyDeviceToDevice, stream);
    hipMemcpyAsync(out_lu,  last_update, (size_t)n_nodes * sizeof(float),
                   hipMemcpyDeviceToDevice, stream);

    // Bn == 100000, divisible by BM=32 -> exact grid.
    dim3 grid(Bn / BM);
    tgn_fused<<<grid, NT, 0, stream>>>(memory, node_idxs, nf, ef, tstamps,
                                       W1, b1, W2, b2, Wih, Whh, bih, bhh,
                                       out_mem, out_msg, out_lu);
}